// Round 2
// baseline (159.752 us; speedup 1.0000x reference)
//
#include <hip/hip_runtime.h>
#include <hip/hip_fp16.h>

// SpaceCarverGridSampler: nearest grid-sample with 3x3 hole-fix search.
// depth: (B=8, C=1, H=512, W=512) f32, grid: (B, 1024, 1024, 2) f32
// out:   (B, 1, 1024, 1024) f32
//
// Round 10: binder = per-lane gather request service (~0.34 req/cyc/CU),
// not distinct-line count (r9: redirecting 30% of requests to a shared
// line gave only -8.5%) and not L1 behavior (r7 sc0 neutral) and not
// per-wave ILP (r8 neutral). So: eliminate OOB requests entirely via
// exec-masked conditional gathers -- masked-off lanes issue NO memory
// request. ~29.7% of all lane-requests removed. r[] init 0 + conditional
// overwrite also deletes the select pass. Table f16 + XCD-affine batch
// swizzle + 16 px/thread retained.

#define SC_B  8
#define SC_H  512
#define SC_W  512

// padded fixed image: rows/cols cover [-1, 512] -> 514 x 514, stride 516
#define FP_H  514
#define FP_W  514
#define FP_S  516
#define FP_BATCH (FP_H * FP_S)

typedef float fvec4 __attribute__((ext_vector_type(4)));
typedef float fvec2 __attribute__((ext_vector_type(2)));

// ---------------- Pass 1: build fixedPad (f16), XCD-swizzled ----------------
__global__ __launch_bounds__(256) void build_fixed_kernel(
    const float* __restrict__ depth,
    __half* __restrict__ fixedPad)
{
    int b     = blockIdx.x & 7;
    int local = blockIdx.x >> 3;
    int t = local * 256 + threadIdx.x;
    if (t >= FP_H * FP_W) return;
    int py = t / FP_W;       // 0..513
    int px = t - py * FP_W;  // 0..513
    int y = py - 1;          // -1..512  (source-center coord)
    int x = px - 1;

    const float* __restrict__ img = depth + (size_t)b * (SC_H * SC_W);

    // center first, then ring in row-major (dy,dx) order
    const int dys[9] = { 0, -1, -1, -1,  0, 0,  1, 1, 1 };
    const int dxs[9] = { 0, -1,  0,  1, -1, 1, -1, 0, 1 };

    float v[9];
    bool  inb[9];
    #pragma unroll
    for (int k = 0; k < 9; ++k) {
        int cy = y + dys[k];
        int cx = x + dxs[k];
        inb[k] = (cy >= 0) & (cy < SC_H) & (cx >= 0) & (cx < SC_W);
        int cyc = min(max(cy, 0), SC_H - 1);
        int cxc = min(max(cx, 0), SC_W - 1);
        v[k] = img[cyc * SC_W + cxc];   // coalesced neighborhoods, L1-friendly
    }

    // reverse-priority branch-free select: lowest k (center) wins
    float result = 0.0f;
    #pragma unroll
    for (int k = 8; k >= 0; --k) {
        bool valid = inb[k] & (v[k] != 0.0f);
        result = valid ? v[k] : result;
    }

    fixedPad[(size_t)b * FP_BATCH + py * FP_S + px] = __float2half(result);
}

// ---------------- Pass 2: sample (exec-masked gathers) ----------------------
__device__ __forceinline__ void coord_to_idx(float gx, float gy,
                                             int& lin, bool& inrange)
{
    // unnormalize, align_corners=True, exact fp32 op order as reference
    float x = (gx + 1.0f) * 0.5f * (float)(SC_W - 1);
    float y = (gy + 1.0f) * 0.5f * (float)(SC_H - 1);
    int ix = (int)rintf(x);   // jnp.round = RNE = rintf
    int iy = (int)rintf(y);

    // any candidate in-bounds iff ix in [-1, W] and iy in [-1, H]
    inrange = (ix >= -1) & (ix <= SC_W) & (iy >= -1) & (iy <= SC_H);
    // clamped (always-safe) index; only consumed under the inrange mask
    int px = min(max(ix + 1, 0), FP_W - 1);
    int py = min(max(iy + 1, 0), FP_H - 1);
    lin = py * FP_S + px;
}

// px/batch = 1<<20; grid fvec4s per batch = 1<<19.
// Block = 256 threads x 8 fvec4s (16 px) = 2048 fvec4s/block.
// 256 blocks/batch; 2048 total. batch = blockIdx.x & 7 -> XCD-affine.
__global__ __launch_bounds__(256) void sample_kernel(
    const __half* __restrict__ fixedPad,
    const float* __restrict__ grid,
    float* __restrict__ out)
{
    int b     = blockIdx.x & 7;
    int local = blockIdx.x >> 3;            // 0..255 within batch
    int base4 = (b << 19) + local * 2048;   // global fvec4 index of block start

    const fvec4* __restrict__ g4 = reinterpret_cast<const fvec4*>(grid);
    fvec2* __restrict__ o2 = reinterpret_cast<fvec2*>(out);

    const __half* __restrict__ fp = fixedPad + (size_t)b * FP_BATCH;

    // 8 coalesced non-temporal 16B loads, all issued up front
    fvec4 g[8];
    int j[8];
    #pragma unroll
    for (int k = 0; k < 8; ++k) {
        j[k] = base4 + threadIdx.x + (k << 8);
        g[k] = __builtin_nontemporal_load(&g4[j[k]]);
    }

    // 16 table addresses + in-range flags
    int  lin[16];
    bool inr[16];
    #pragma unroll
    for (int k = 0; k < 8; ++k) {
        coord_to_idx(g[k].x, g[k].y, lin[2 * k],     inr[2 * k]);
        coord_to_idx(g[k].z, g[k].w, lin[2 * k + 1], inr[2 * k + 1]);
    }

    // exec-masked gathers: OOB lanes issue NO memory request at all.
    // r init 0 + conditional overwrite replaces the select pass.
    float r[16];
    #pragma unroll
    for (int k = 0; k < 16; ++k) {
        r[k] = 0.0f;
        if (inr[k]) {
            r[k] = __half2float(fp[lin[k]]);
        }
    }

    #pragma unroll
    for (int k = 0; k < 8; ++k) {
        fvec2 val;
        val.x = r[2 * k];
        val.y = r[2 * k + 1];
        __builtin_nontemporal_store(val, &o2[j[k]]);
    }
}

// ---------------- Fallback (ws too small): round-1 style ----------------
__global__ __launch_bounds__(256) void fallback_kernel(
    const float* __restrict__ depth,
    const float* __restrict__ grid,
    float* __restrict__ out,
    int total)
{
    int idx = blockIdx.x * blockDim.x + threadIdx.x;
    if (idx >= total) return;
    int b = idx >> 20;
    float2 g = reinterpret_cast<const float2*>(grid)[idx];
    float x = (g.x + 1.0f) * 0.5f * (float)(SC_W - 1);
    float y = (g.y + 1.0f) * 0.5f * (float)(SC_H - 1);
    int ix = (int)rintf(x);
    int iy = (int)rintf(y);
    const float* __restrict__ img = depth + (size_t)b * (SC_H * SC_W);
    const int dys[9] = { 0, -1, -1, -1,  0, 0,  1, 1, 1 };
    const int dxs[9] = { 0, -1,  0,  1, -1, 1, -1, 0, 1 };
    float result = 0.0f;
    #pragma unroll
    for (int k = 0; k < 9; ++k) {
        int cy = iy + dys[k];
        int cx = ix + dxs[k];
        if (cy >= 0 && cy < SC_H && cx >= 0 && cx < SC_W) {
            float v = img[cy * SC_W + cx];
            if (v != 0.0f) { result = v; break; }
        }
    }
    out[idx] = result;
}

extern "C" void kernel_launch(void* const* d_in, const int* in_sizes, int n_in,
                              void* d_out, int out_size, void* d_ws, size_t ws_size,
                              hipStream_t stream) {
    const float* depth = (const float*)d_in[0];  // (8,1,512,512)
    const float* grid  = (const float*)d_in[1];  // (8,1024,1024,2)
    float* out = (float*)d_out;                  // (8,1,1024,1024)

    size_t need = (size_t)SC_B * FP_BATCH * sizeof(__half);  // ~4.3 MB
    if (ws_size >= need && out_size == (SC_B << 20)) {
        __half* fixedPad = (__half*)d_ws;

        // Pass 1: 514*514 px per batch, XCD-swizzled (1033 blocks/batch)
        int per_batch = FP_H * FP_W;
        int blocks_per_batch = (per_batch + 255) / 256;
        dim3 b1(256);
        dim3 g1(blocks_per_batch * SC_B);
        build_fixed_kernel<<<g1, b1, 0, stream>>>(depth, fixedPad);

        // Pass 2: XCD-swizzled, exec-masked gathers. 2048 blocks.
        dim3 b2(256);
        dim3 g2(2048);
        sample_kernel<<<g2, b2, 0, stream>>>(fixedPad, grid, out);
    } else {
        int total = out_size;
        dim3 block(256);
        dim3 gridDim((total + block.x - 1) / block.x);
        fallback_kernel<<<gridDim, block, 0, stream>>>(depth, grid, out, total);
    }
}

// Round 3
// 143.200 us; speedup vs baseline: 1.1156x; 1.1156x over previous
//
#include <hip/hip_runtime.h>
#include <hip/hip_fp16.h>

// SpaceCarverGridSampler: nearest grid-sample with 3x3 hole-fix search.
// depth: (B=8, C=1, H=512, W=512) f32, grid: (B, 1024, 1024, 2) f32
// out:   (B, 1, 1024, 1024) f32
//
// Round 11: r10 post-mortem -- per-lane exec-masked gathers tripled VGPR
// (44->132), dropped occupancy 33->10% and serialized the gather issue:
// sample 39.8->73.5us. REVERT sample to the r9/r1 proven form (line-0
// collapse for OOB; requests that hit the L1-hot line 0 never consume the
// scarce L2-request/miss-tracking resource). New this round: build_fixed
// vectorized 4 px/thread -- 3x6 register window shared across 4 outputs
// (18 loads vs 36, clamps amortized), __half2 paired stores.

#define SC_B  8
#define SC_H  512
#define SC_W  512

// padded fixed image: rows/cols cover [-1, 512] -> 514 x 514, stride 516
#define FP_H  514
#define FP_W  514
#define FP_S  516
#define FP_BATCH (FP_H * FP_S)

// build pass geometry: 4 consecutive px per thread
#define QPR   129                  // quads per row = ceil(514/4)
#define QUADS_PER_BATCH (FP_H * QPR)   // 514*129 = 66306

typedef float fvec4 __attribute__((ext_vector_type(4)));
typedef float fvec2 __attribute__((ext_vector_type(2)));

// ---------------- Pass 1: build fixedPad (f16), 4 px/thread ----------------
__global__ __launch_bounds__(256) void build_fixed_kernel(
    const float* __restrict__ depth,
    __half* __restrict__ fixedPad)
{
    int b     = blockIdx.x & 7;            // XCD-affine batch
    int local = blockIdx.x >> 3;
    int t = local * 256 + threadIdx.x;
    if (t >= QUADS_PER_BATCH) return;
    int py  = t / QPR;                     // 0..513
    int qx  = t - py * QPR;
    int px0 = qx * 4;                      // 0..512
    int y   = py - 1;                      // -1..512 (source-center row)
    int x0  = px0 - 1;                     // source-center col of first px

    const float* __restrict__ img = depth + (size_t)b * (SC_H * SC_W);

    // shared 3-row x 6-col register window: rows y-1..y+1, cols x0-1..x0+4
    bool rv[3]; int ryc[3];
    #pragma unroll
    for (int r = 0; r < 3; ++r) {
        int cy = y - 1 + r;
        rv[r]  = (cy >= 0) & (cy < SC_H);
        ryc[r] = min(max(cy, 0), SC_H - 1);
    }
    bool cv[6]; int cxc[6];
    #pragma unroll
    for (int c = 0; c < 6; ++c) {
        int cx = x0 - 1 + c;
        cv[c]  = (cx >= 0) & (cx < SC_W);
        cxc[c] = min(max(cx, 0), SC_W - 1);
    }

    float v[3][6];
    #pragma unroll
    for (int r = 0; r < 3; ++r) {
        const float* __restrict__ row = img + ryc[r] * SC_W;
        #pragma unroll
        for (int c = 0; c < 6; ++c) {
            v[r][c] = row[cxc[c]];
        }
    }

    // center first, then ring in row-major (dy,dx) order (priority order)
    const int dys[9] = { 0, -1, -1, -1,  0, 0,  1, 1, 1 };
    const int dxs[9] = { 0, -1,  0,  1, -1, 1, -1, 0, 1 };

    float res[4];
    #pragma unroll
    for (int i = 0; i < 4; ++i) {
        // output px = px0+i; its center col sits at window col i+1
        float result = 0.0f;
        #pragma unroll
        for (int k = 8; k >= 0; --k) {
            int r = dys[k] + 1;
            int c = i + 1 + dxs[k];
            bool valid = rv[r] & cv[c] & (v[r][c] != 0.0f);
            result = valid ? v[r][c] : result;
        }
        res[i] = result;
    }

    // paired __half2 stores (px0 even -> 4B aligned; pad cols 514/515 are
    // never read by the sampler, safe to write junk there for qx==128)
    __half* dst = fixedPad + (size_t)b * FP_BATCH + py * FP_S + px0;
    __half2* d2 = reinterpret_cast<__half2*>(dst);
    d2[0] = __floats2half2_rn(res[0], res[1]);
    d2[1] = __floats2half2_rn(res[2], res[3]);
}

// ---------------- Pass 2: sample (r9/r1 proven form) ------------------------
__device__ __forceinline__ void coord_to_idx(float gx, float gy,
                                             int& lin, bool& inrange)
{
    // unnormalize, align_corners=True, exact fp32 op order as reference
    float x = (gx + 1.0f) * 0.5f * (float)(SC_W - 1);
    float y = (gy + 1.0f) * 0.5f * (float)(SC_H - 1);
    int ix = (int)rintf(x);   // jnp.round = RNE = rintf
    int iy = (int)rintf(y);

    // any candidate in-bounds iff ix in [-1, W] and iy in [-1, H]
    inrange = (ix >= -1) & (ix <= SC_W) & (iy >= -1) & (iy <= SC_H);
    int px = min(max(ix + 1, 0), FP_W - 1);
    int py = min(max(iy + 1, 0), FP_H - 1);
    // OOB lanes collapse to line 0 (shared, L1-hot) instead of distinct
    // clamped edge positions: these never consume L2-request service.
    lin = inrange ? (py * FP_S + px) : 0;
}

// px/batch = 1<<20; grid fvec4s per batch = 1<<19.
// Block = 256 threads x 8 fvec4s (16 px) = 2048 fvec4s/block.
// 256 blocks/batch; 2048 total. batch = blockIdx.x & 7 -> XCD-affine.
__global__ __launch_bounds__(256) void sample_kernel(
    const __half* __restrict__ fixedPad,
    const float* __restrict__ grid,
    float* __restrict__ out)
{
    int b     = blockIdx.x & 7;
    int local = blockIdx.x >> 3;            // 0..255 within batch
    int base4 = (b << 19) + local * 2048;   // global fvec4 index of block start

    const fvec4* __restrict__ g4 = reinterpret_cast<const fvec4*>(grid);
    fvec2* __restrict__ o2 = reinterpret_cast<fvec2*>(out);

    const __half* __restrict__ fp = fixedPad + (size_t)b * FP_BATCH;

    // 8 coalesced non-temporal 16B loads, all issued up front
    fvec4 g[8];
    int j[8];
    #pragma unroll
    for (int k = 0; k < 8; ++k) {
        j[k] = base4 + threadIdx.x + (k << 8);
        g[k] = __builtin_nontemporal_load(&g4[j[k]]);
    }

    // 16 table addresses + in-range flags
    int  lin[16];
    bool inr[16];
    #pragma unroll
    for (int k = 0; k < 8; ++k) {
        coord_to_idx(g[k].x, g[k].y, lin[2 * k],     inr[2 * k]);
        coord_to_idx(g[k].z, g[k].w, lin[2 * k + 1], inr[2 * k + 1]);
    }

    // 16 independent gathers (OOB lanes all hit line 0); let the compiler
    // batch-issue and fine-grain the waitcnts
    float r[16];
    #pragma unroll
    for (int k = 0; k < 16; ++k) {
        r[k] = __half2float(fp[lin[k]]);
    }
    #pragma unroll
    for (int k = 0; k < 16; ++k) {
        r[k] = inr[k] ? r[k] : 0.0f;
    }

    #pragma unroll
    for (int k = 0; k < 8; ++k) {
        fvec2 val;
        val.x = r[2 * k];
        val.y = r[2 * k + 1];
        __builtin_nontemporal_store(val, &o2[j[k]]);
    }
}

// ---------------- Fallback (ws too small): round-1 style ----------------
__global__ __launch_bounds__(256) void fallback_kernel(
    const float* __restrict__ depth,
    const float* __restrict__ grid,
    float* __restrict__ out,
    int total)
{
    int idx = blockIdx.x * blockDim.x + threadIdx.x;
    if (idx >= total) return;
    int b = idx >> 20;
    float2 g = reinterpret_cast<const float2*>(grid)[idx];
    float x = (g.x + 1.0f) * 0.5f * (float)(SC_W - 1);
    float y = (g.y + 1.0f) * 0.5f * (float)(SC_H - 1);
    int ix = (int)rintf(x);
    int iy = (int)rintf(y);
    const float* __restrict__ img = depth + (size_t)b * (SC_H * SC_W);
    const int dys[9] = { 0, -1, -1, -1,  0, 0,  1, 1, 1 };
    const int dxs[9] = { 0, -1,  0,  1, -1, 1, -1, 0, 1 };
    float result = 0.0f;
    #pragma unroll
    for (int k = 0; k < 9; ++k) {
        int cy = iy + dys[k];
        int cx = ix + dxs[k];
        if (cy >= 0 && cy < SC_H && cx >= 0 && cx < SC_W) {
            float v = img[cy * SC_W + cx];
            if (v != 0.0f) { result = v; break; }
        }
    }
    out[idx] = result;
}

extern "C" void kernel_launch(void* const* d_in, const int* in_sizes, int n_in,
                              void* d_out, int out_size, void* d_ws, size_t ws_size,
                              hipStream_t stream) {
    const float* depth = (const float*)d_in[0];  // (8,1,512,512)
    const float* grid  = (const float*)d_in[1];  // (8,1024,1024,2)
    float* out = (float*)d_out;                  // (8,1,1024,1024)

    size_t need = (size_t)SC_B * FP_BATCH * sizeof(__half);  // ~4.3 MB
    if (ws_size >= need && out_size == (SC_B << 20)) {
        __half* fixedPad = (__half*)d_ws;

        // Pass 1: 66306 quad-tasks per batch, XCD-swizzled (260 blocks/batch)
        int blocks_per_batch = (QUADS_PER_BATCH + 255) / 256;  // 260
        dim3 b1(256);
        dim3 g1(blocks_per_batch * SC_B);
        build_fixed_kernel<<<g1, b1, 0, stream>>>(depth, fixedPad);

        // Pass 2: XCD-swizzled, 16 px/thread. 2048 blocks.
        dim3 b2(256);
        dim3 g2(2048);
        sample_kernel<<<g2, b2, 0, stream>>>(fixedPad, grid, out);
    } else {
        int total = out_size;
        dim3 block(256);
        dim3 gridDim((total + block.x - 1) / block.x);
        fallback_kernel<<<gridDim, block, 0, stream>>>(depth, grid, out, total);
    }
}

// Round 4
// 139.603 us; speedup vs baseline: 1.1443x; 1.0258x over previous
//
#include <hip/hip_runtime.h>
#include <hip/hip_fp16.h>

// SpaceCarverGridSampler: nearest grid-sample with 3x3 hole-fix search.
// depth: (B=8, C=1, H=512, W=512) f32, grid: (B, 1024, 1024, 2) f32
// out:   (B, 1, 1024, 1024) f32
//
// Round 12: revert to the exact r9 config (best measured, 139.6us).
// Cross-round A/B: r1->r3 isolated the quad build as +3.6us (stride-2
// window loads + t/129 div + row-tail misalignment ate the load-sharing
// win) -> build back to 1 px/thread. Sample keeps the r9 line-0 collapse
// (-3.7us isolated, r0->r1). Gather path sits at ~0.22 miss-lines/cyc/CU
// (~7.1 L2 req/cyc/XCD): ILP x2 neutral (r8), requests -30% -> -8.5%
// (r9), exec-masking catastrophic via occupancy (r10). Remaining lever
// (per-CU sort) EV ~-8us at r10-class risk: declined.

#define SC_B  8
#define SC_H  512
#define SC_W  512

// padded fixed image: rows/cols cover [-1, 512] -> 514 x 514, stride 516
#define FP_H  514
#define FP_W  514
#define FP_S  516
#define FP_BATCH (FP_H * FP_S)

typedef float fvec4 __attribute__((ext_vector_type(4)));
typedef float fvec2 __attribute__((ext_vector_type(2)));

// ---------------- Pass 1: build fixedPad (f16), XCD-swizzled ----------------
__global__ __launch_bounds__(256) void build_fixed_kernel(
    const float* __restrict__ depth,
    __half* __restrict__ fixedPad)
{
    int b     = blockIdx.x & 7;
    int local = blockIdx.x >> 3;
    int t = local * 256 + threadIdx.x;
    if (t >= FP_H * FP_W) return;
    int py = t / FP_W;       // 0..513
    int px = t - py * FP_W;  // 0..513
    int y = py - 1;          // -1..512  (source-center coord)
    int x = px - 1;

    const float* __restrict__ img = depth + (size_t)b * (SC_H * SC_W);

    // center first, then ring in row-major (dy,dx) order
    const int dys[9] = { 0, -1, -1, -1,  0, 0,  1, 1, 1 };
    const int dxs[9] = { 0, -1,  0,  1, -1, 1, -1, 0, 1 };

    float v[9];
    bool  inb[9];
    #pragma unroll
    for (int k = 0; k < 9; ++k) {
        int cy = y + dys[k];
        int cx = x + dxs[k];
        inb[k] = (cy >= 0) & (cy < SC_H) & (cx >= 0) & (cx < SC_W);
        int cyc = min(max(cy, 0), SC_H - 1);
        int cxc = min(max(cx, 0), SC_W - 1);
        v[k] = img[cyc * SC_W + cxc];   // coalesced neighborhoods, L1-friendly
    }

    // reverse-priority branch-free select: lowest k (center) wins
    float result = 0.0f;
    #pragma unroll
    for (int k = 8; k >= 0; --k) {
        bool valid = inb[k] & (v[k] != 0.0f);
        result = valid ? v[k] : result;
    }

    fixedPad[(size_t)b * FP_BATCH + py * FP_S + px] = __float2half(result);
}

// ---------------- Pass 2: sample (16 gathers in flight per thread) ----------
__device__ __forceinline__ void coord_to_idx(float gx, float gy,
                                             int& lin, bool& inrange)
{
    // unnormalize, align_corners=True, exact fp32 op order as reference
    float x = (gx + 1.0f) * 0.5f * (float)(SC_W - 1);
    float y = (gy + 1.0f) * 0.5f * (float)(SC_H - 1);
    int ix = (int)rintf(x);   // jnp.round = RNE = rintf
    int iy = (int)rintf(y);

    // any candidate in-bounds iff ix in [-1, W] and iy in [-1, H]
    inrange = (ix >= -1) & (ix <= SC_W) & (iy >= -1) & (iy <= SC_H);
    int px = min(max(ix + 1, 0), FP_W - 1);
    int py = min(max(iy + 1, 0), FP_H - 1);
    // OOB lanes collapse to line 0 (shared, L1-hot) instead of distinct
    // clamped edge positions: ~30% fewer distinct-line gather requests.
    lin = inrange ? (py * FP_S + px) : 0;
}

// px/batch = 1<<20; grid fvec4s per batch = 1<<19.
// Block = 256 threads x 8 fvec4s (16 px) = 2048 fvec4s/block.
// 256 blocks/batch; 2048 total. batch = blockIdx.x & 7 -> XCD-affine.
__global__ __launch_bounds__(256) void sample_kernel(
    const __half* __restrict__ fixedPad,
    const float* __restrict__ grid,
    float* __restrict__ out)
{
    int b     = blockIdx.x & 7;
    int local = blockIdx.x >> 3;            // 0..255 within batch
    int base4 = (b << 19) + local * 2048;   // global fvec4 index of block start

    const fvec4* __restrict__ g4 = reinterpret_cast<const fvec4*>(grid);
    fvec2* __restrict__ o2 = reinterpret_cast<fvec2*>(out);

    const __half* __restrict__ fp = fixedPad + (size_t)b * FP_BATCH;

    // 8 coalesced non-temporal 16B loads, all issued up front
    fvec4 g[8];
    int j[8];
    #pragma unroll
    for (int k = 0; k < 8; ++k) {
        j[k] = base4 + threadIdx.x + (k << 8);
        g[k] = __builtin_nontemporal_load(&g4[j[k]]);
    }

    // 16 table addresses + in-range flags
    int  lin[16];
    bool inr[16];
    #pragma unroll
    for (int k = 0; k < 8; ++k) {
        coord_to_idx(g[k].x, g[k].y, lin[2 * k],     inr[2 * k]);
        coord_to_idx(g[k].z, g[k].w, lin[2 * k + 1], inr[2 * k + 1]);
    }

    // 16 independent gathers (OOB lanes all hit line 0); let the compiler
    // batch-issue and fine-grain the waitcnts
    float r[16];
    #pragma unroll
    for (int k = 0; k < 16; ++k) {
        r[k] = __half2float(fp[lin[k]]);
    }
    #pragma unroll
    for (int k = 0; k < 16; ++k) {
        r[k] = inr[k] ? r[k] : 0.0f;
    }

    #pragma unroll
    for (int k = 0; k < 8; ++k) {
        fvec2 val;
        val.x = r[2 * k];
        val.y = r[2 * k + 1];
        __builtin_nontemporal_store(val, &o2[j[k]]);
    }
}

// ---------------- Fallback (ws too small): round-1 style ----------------
__global__ __launch_bounds__(256) void fallback_kernel(
    const float* __restrict__ depth,
    const float* __restrict__ grid,
    float* __restrict__ out,
    int total)
{
    int idx = blockIdx.x * blockDim.x + threadIdx.x;
    if (idx >= total) return;
    int b = idx >> 20;
    float2 g = reinterpret_cast<const float2*>(grid)[idx];
    float x = (g.x + 1.0f) * 0.5f * (float)(SC_W - 1);
    float y = (g.y + 1.0f) * 0.5f * (float)(SC_H - 1);
    int ix = (int)rintf(x);
    int iy = (int)rintf(y);
    const float* __restrict__ img = depth + (size_t)b * (SC_H * SC_W);
    const int dys[9] = { 0, -1, -1, -1,  0, 0,  1, 1, 1 };
    const int dxs[9] = { 0, -1,  0,  1, -1, 1, -1, 0, 1 };
    float result = 0.0f;
    #pragma unroll
    for (int k = 0; k < 9; ++k) {
        int cy = iy + dys[k];
        int cx = ix + dxs[k];
        if (cy >= 0 && cy < SC_H && cx >= 0 && cx < SC_W) {
            float v = img[cy * SC_W + cx];
            if (v != 0.0f) { result = v; break; }
        }
    }
    out[idx] = result;
}

extern "C" void kernel_launch(void* const* d_in, const int* in_sizes, int n_in,
                              void* d_out, int out_size, void* d_ws, size_t ws_size,
                              hipStream_t stream) {
    const float* depth = (const float*)d_in[0];  // (8,1,512,512)
    const float* grid  = (const float*)d_in[1];  // (8,1024,1024,2)
    float* out = (float*)d_out;                  // (8,1,1024,1024)

    size_t need = (size_t)SC_B * FP_BATCH * sizeof(__half);  // ~4.3 MB
    if (ws_size >= need && out_size == (SC_B << 20)) {
        __half* fixedPad = (__half*)d_ws;

        // Pass 1: 514*514 px per batch, XCD-swizzled (1033 blocks/batch)
        int per_batch = FP_H * FP_W;
        int blocks_per_batch = (per_batch + 255) / 256;
        dim3 b1(256);
        dim3 g1(blocks_per_batch * SC_B);
        build_fixed_kernel<<<g1, b1, 0, stream>>>(depth, fixedPad);

        // Pass 2: XCD-swizzled, 16 px/thread. 2048 blocks.
        dim3 b2(256);
        dim3 g2(2048);
        sample_kernel<<<g2, b2, 0, stream>>>(fixedPad, grid, out);
    } else {
        int total = out_size;
        dim3 block(256);
        dim3 gridDim((total + block.x - 1) / block.x);
        fallback_kernel<<<gridDim, block, 0, stream>>>(depth, grid, out, total);
    }
}

// Round 5
// 138.488 us; speedup vs baseline: 1.1535x; 1.0080x over previous
//
#include <hip/hip_runtime.h>
#include <hip/hip_fp16.h>

// SpaceCarverGridSampler: nearest grid-sample with 3x3 hole-fix search.
// depth: (B=8, C=1, H=512, W=512) f32, grid: (B, 1024, 1024, 2) f32
// out:   (B, 1, 1024, 1024) f32
//
// Round 13: sample kernel untouched (r9 form, reproduced 139.60/139.62
// across rounds -- probes exhausted: ILP x2 neutral, requests -30% ->
// -8.5%, exec-mask catastrophic, sc0 neutral; sort/bin EV ~0 after
// 2 extra 8.4M-sample passes). This round: build pass vertical 2-px
// pairing. r3's quad failed via t/129 div + stride-2 window + row tail;
// this variant has NO integer div (2D grid: x=col-block, y=row-pair,
// z=batch), identical horizontal coalescing to the 1-px kernel, and a
// 4-row x 3-col shared window (12 loads / 2 px = -33% load volume).
// 514 rows = 257 pairs exactly, no tail.

#define SC_B  8
#define SC_H  512
#define SC_W  512

// padded fixed image: rows/cols cover [-1, 512] -> 514 x 514, stride 516
#define FP_H  514
#define FP_W  514
#define FP_S  516
#define FP_BATCH (FP_H * FP_S)

typedef float fvec4 __attribute__((ext_vector_type(4)));
typedef float fvec2 __attribute__((ext_vector_type(2)));

// ---------------- Pass 1: build fixedPad (f16), 2 vertical px/thread --------
__global__ __launch_bounds__(256) void build_fixed_kernel(
    const float* __restrict__ depth,
    __half* __restrict__ fixedPad)
{
    int b   = blockIdx.z;                     // batch
    int px  = blockIdx.x * 256 + threadIdx.x; // 0..767; consecutive lanes -> consecutive px
    if (px >= FP_W) return;
    int py0 = blockIdx.y * 2;                 // 0,2,...,512 (257 pairs exact)
    int x   = px - 1;                         // source-center col
    int y0  = py0 - 1;                        // source-center row of first output

    const float* __restrict__ img = depth + (size_t)b * (SC_H * SC_W);

    // shared register window: rows y0-1..y0+2, cols x-1..x+1 (12 loads / 2 px)
    bool cv[3]; int cxc[3];
    #pragma unroll
    for (int c = 0; c < 3; ++c) {
        int cx = x - 1 + c;
        cv[c]  = (cx >= 0) & (cx < SC_W);
        cxc[c] = min(max(cx, 0), SC_W - 1);
    }
    bool rv[4]; int ryc[4];
    #pragma unroll
    for (int r = 0; r < 4; ++r) {
        int cy = y0 - 1 + r;
        rv[r]  = (cy >= 0) & (cy < SC_H);
        ryc[r] = min(max(cy, 0), SC_H - 1);
    }

    float v[4][3];
    #pragma unroll
    for (int r = 0; r < 4; ++r) {
        const float* __restrict__ row = img + ryc[r] * SC_W;
        #pragma unroll
        for (int c = 0; c < 3; ++c) {
            v[r][c] = row[cxc[c]];            // coalesced + L1-broadcast friendly
        }
    }

    // center first, then ring in row-major (dy,dx) order (priority order)
    const int dys[9] = { 0, -1, -1, -1,  0, 0,  1, 1, 1 };
    const int dxs[9] = { 0, -1,  0,  1, -1, 1, -1, 0, 1 };

    __half* dst = fixedPad + (size_t)b * FP_BATCH + py0 * FP_S + px;
    #pragma unroll
    for (int i = 0; i < 2; ++i) {             // output rows py0, py0+1
        // reverse-priority branch-free select: lowest k (center) wins
        float result = 0.0f;
        #pragma unroll
        for (int k = 8; k >= 0; --k) {
            int r = 1 + i + dys[k];           // sub-window rows i..i+2
            int c = 1 + dxs[k];
            bool valid = rv[r] & cv[c] & (v[r][c] != 0.0f);
            result = valid ? v[r][c] : result;
        }
        dst[(size_t)i * FP_S] = __float2half(result);
    }
}

// ---------------- Pass 2: sample (r9 proven form, untouched) ----------------
__device__ __forceinline__ void coord_to_idx(float gx, float gy,
                                             int& lin, bool& inrange)
{
    // unnormalize, align_corners=True, exact fp32 op order as reference
    float x = (gx + 1.0f) * 0.5f * (float)(SC_W - 1);
    float y = (gy + 1.0f) * 0.5f * (float)(SC_H - 1);
    int ix = (int)rintf(x);   // jnp.round = RNE = rintf
    int iy = (int)rintf(y);

    // any candidate in-bounds iff ix in [-1, W] and iy in [-1, H]
    inrange = (ix >= -1) & (ix <= SC_W) & (iy >= -1) & (iy <= SC_H);
    int px = min(max(ix + 1, 0), FP_W - 1);
    int py = min(max(iy + 1, 0), FP_H - 1);
    // OOB lanes collapse to line 0 (shared, L1-hot) instead of distinct
    // clamped edge positions: ~30% fewer distinct-line gather requests.
    lin = inrange ? (py * FP_S + px) : 0;
}

// px/batch = 1<<20; grid fvec4s per batch = 1<<19.
// Block = 256 threads x 8 fvec4s (16 px) = 2048 fvec4s/block.
// 256 blocks/batch; 2048 total. batch = blockIdx.x & 7 -> XCD-affine.
__global__ __launch_bounds__(256) void sample_kernel(
    const __half* __restrict__ fixedPad,
    const float* __restrict__ grid,
    float* __restrict__ out)
{
    int b     = blockIdx.x & 7;
    int local = blockIdx.x >> 3;            // 0..255 within batch
    int base4 = (b << 19) + local * 2048;   // global fvec4 index of block start

    const fvec4* __restrict__ g4 = reinterpret_cast<const fvec4*>(grid);
    fvec2* __restrict__ o2 = reinterpret_cast<fvec2*>(out);

    const __half* __restrict__ fp = fixedPad + (size_t)b * FP_BATCH;

    // 8 coalesced non-temporal 16B loads, all issued up front
    fvec4 g[8];
    int j[8];
    #pragma unroll
    for (int k = 0; k < 8; ++k) {
        j[k] = base4 + threadIdx.x + (k << 8);
        g[k] = __builtin_nontemporal_load(&g4[j[k]]);
    }

    // 16 table addresses + in-range flags
    int  lin[16];
    bool inr[16];
    #pragma unroll
    for (int k = 0; k < 8; ++k) {
        coord_to_idx(g[k].x, g[k].y, lin[2 * k],     inr[2 * k]);
        coord_to_idx(g[k].z, g[k].w, lin[2 * k + 1], inr[2 * k + 1]);
    }

    // 16 independent gathers (OOB lanes all hit line 0); let the compiler
    // batch-issue and fine-grain the waitcnts
    float r[16];
    #pragma unroll
    for (int k = 0; k < 16; ++k) {
        r[k] = __half2float(fp[lin[k]]);
    }
    #pragma unroll
    for (int k = 0; k < 16; ++k) {
        r[k] = inr[k] ? r[k] : 0.0f;
    }

    #pragma unroll
    for (int k = 0; k < 8; ++k) {
        fvec2 val;
        val.x = r[2 * k];
        val.y = r[2 * k + 1];
        __builtin_nontemporal_store(val, &o2[j[k]]);
    }
}

// ---------------- Fallback (ws too small): round-1 style ----------------
__global__ __launch_bounds__(256) void fallback_kernel(
    const float* __restrict__ depth,
    const float* __restrict__ grid,
    float* __restrict__ out,
    int total)
{
    int idx = blockIdx.x * blockDim.x + threadIdx.x;
    if (idx >= total) return;
    int b = idx >> 20;
    float2 g = reinterpret_cast<const float2*>(grid)[idx];
    float x = (g.x + 1.0f) * 0.5f * (float)(SC_W - 1);
    float y = (g.y + 1.0f) * 0.5f * (float)(SC_H - 1);
    int ix = (int)rintf(x);
    int iy = (int)rintf(y);
    const float* __restrict__ img = depth + (size_t)b * (SC_H * SC_W);
    const int dys[9] = { 0, -1, -1, -1,  0, 0,  1, 1, 1 };
    const int dxs[9] = { 0, -1,  0,  1, -1, 1, -1, 0, 1 };
    float result = 0.0f;
    #pragma unroll
    for (int k = 0; k < 9; ++k) {
        int cy = iy + dys[k];
        int cx = ix + dxs[k];
        if (cy >= 0 && cy < SC_H && cx >= 0 && cx < SC_W) {
            float v = img[cy * SC_W + cx];
            if (v != 0.0f) { result = v; break; }
        }
    }
    out[idx] = result;
}

extern "C" void kernel_launch(void* const* d_in, const int* in_sizes, int n_in,
                              void* d_out, int out_size, void* d_ws, size_t ws_size,
                              hipStream_t stream) {
    const float* depth = (const float*)d_in[0];  // (8,1,512,512)
    const float* grid  = (const float*)d_in[1];  // (8,1024,1024,2)
    float* out = (float*)d_out;                  // (8,1,1024,1024)

    size_t need = (size_t)SC_B * FP_BATCH * sizeof(__half);  // ~4.3 MB
    if (ws_size >= need && out_size == (SC_B << 20)) {
        __half* fixedPad = (__half*)d_ws;

        // Pass 1: 2D grid -- x: 3 col-blocks of 256 px, y: 257 row-pairs,
        // z: 8 batches. No integer div; no tail.
        dim3 b1(256);
        dim3 g1(3, 257, SC_B);
        build_fixed_kernel<<<g1, b1, 0, stream>>>(depth, fixedPad);

        // Pass 2: XCD-swizzled, 16 px/thread. 2048 blocks.
        dim3 b2(256);
        dim3 g2(2048);
        sample_kernel<<<g2, b2, 0, stream>>>(fixedPad, grid, out);
    } else {
        int total = out_size;
        dim3 block(256);
        dim3 gridDim((total + block.x - 1) / block.x);
        fallback_kernel<<<gridDim, block, 0, stream>>>(depth, grid, out, total);
    }
}